// Round 3
// baseline (490.803 us; speedup 1.0000x reference)
//
#include <hip/hip_runtime.h>
#include <math.h>

#define NE 8
#define NH 2048
#define NI 1024
#define NT 512
#define NTOPK 2
#define NR 16
#define NGROUP 64
#define NPAIR (NT*NTOPK)   // 1024

typedef short bf16x8 __attribute__((ext_vector_type(8)));
typedef float f32x16 __attribute__((ext_vector_type(16)));
typedef unsigned int u32;

#define MFMA32 __builtin_amdgcn_mfma_f32_32x32x16_bf16

__device__ const float NF4_TAB[16] = {
    -1.0f, -0.6961928009986877f, -0.5250730514526367f, -0.39491748809814453f,
    -0.28444138169288635f, -0.18477343022823334f, -0.09105003625154495f, 0.0f,
    0.07958029955625534f, 0.16093020141124725f, 0.24611230194568634f,
    0.33791524171829224f, 0.44070982933044434f, 0.5626170039176941f,
    0.7229568362236328f, 1.0f};

// ---------------- workspace layout (bytes) ----------------
#define OFF_EXPOFF 0         // int[16]
#define OFF_TOK    256       // int[1024]
#define OFF_EXP    4352      // int[1024]
#define OFF_W      8448      // float[1024]
#define OFF_XAG    12544     // ushort[1024*16] bf16
#define OFF_XAU    45312     // ushort[1024*16]
#define OFF_HA     78080     // ushort[1024*16]
#define OFF_XCT    131072    // ushort[NH/8][NPAIR][8] transposed compact x (4 MB)
#define OFF_GU     4325376   // ushort[2*1024*1024] gate|up results (4 MB)
#define OFF_HT     8519680   // ushort[NI/8][NPAIR][8] transposed h (2 MB)

__device__ inline u32 f2bf(float f) {
    return (__float_as_uint(f) + 0x8000u) >> 16;
}
__device__ inline u32 bfpack2(float a, float b) {
    return ((__float_as_uint(a) + 0x8000u) >> 16) |
           ((__float_as_uint(b) + 0x8000u) & 0xFFFF0000u);
}
__device__ inline bf16x8 asbf(uint4 w) {
    union { uint4 u; bf16x8 b; } c; c.u = w; return c.b;
}
__device__ inline bf16x8 bfzero() { return asbf(make_uint4(0,0,0,0)); }
__device__ inline float bf2f(u32 v) { return __uint_as_float(v << 16); }

// async global->LDS: per-lane global addr, LDS dest = wave-uniform base + lane*16
__device__ __forceinline__ void stage16(const void* g, void* l) {
    __builtin_amdgcn_global_load_lds(
        (const __attribute__((address_space(1))) u32*)g,
        (__attribute__((address_space(3))) u32*)l, 16, 0, 0);
}

// -------- kernel 1: routing compaction --------
__global__ __launch_bounds__(1024) void k_route(const int* __restrict__ idx,
                                                const float* __restrict__ w,
                                                int* expert_off, int* ptok,
                                                int* pexp, float* pw) {
    __shared__ int cnt[NE], off[NE + 1], cur[NE];
    int tid = threadIdx.x;
    if (tid < NE) cnt[tid] = 0;
    __syncthreads();
    int e = idx[tid];
    float wt = w[tid];
    int t = tid >> 1;
    atomicAdd(&cnt[e], 1);
    __syncthreads();
    if (tid == 0) {
        off[0] = 0;
        for (int i = 0; i < NE; i++) off[i + 1] = off[i] + cnt[i];
    }
    __syncthreads();
    if (tid < NE) cur[tid] = off[tid];
    __syncthreads();
    int pos = atomicAdd(&cur[e], 1);
    ptok[pos] = t; pexp[pos] = e; pw[pos] = wt;
    if (tid <= NE) expert_off[tid] = off[tid];
}

// -------- kernel 2: gather + transpose x -> xcT[k/8][p][8] bf16 --------
// One block per pair row; coalesced f32 reads, 16B store per thread.
__global__ __launch_bounds__(256) void k_xg(const float* __restrict__ x,
                                            const int* __restrict__ ptok,
                                            unsigned short* __restrict__ xcT) {
    int p = blockIdx.x;
    int t = ptok[p];
    int k = threadIdx.x * 8;
    const float* xr = x + (size_t)t * NH + k;
    float4 v0 = *(const float4*)xr;
    float4 v1 = *(const float4*)(xr + 4);
    uint4 w;
    w.x = bfpack2(v0.x, v0.y); w.y = bfpack2(v0.z, v0.w);
    w.z = bfpack2(v1.x, v1.y); w.w = bfpack2(v1.z, v1.w);
    *(uint4*)(xcT + ((size_t)(k >> 3) * NPAIR + p) * 8) = w;
}

// -------- kernel 3: xA_g[p][r], xA_u[p][r] --------
__global__ __launch_bounds__(256) void k_xA(const float* __restrict__ x,
                                            const float* __restrict__ gA,
                                            const float* __restrict__ uA,
                                            const int* __restrict__ ptok,
                                            const int* __restrict__ pexp,
                                            unsigned short* __restrict__ xAg,
                                            unsigned short* __restrict__ xAu) {
    int p = blockIdx.x;
    int t = ptok[p], e = pexp[p];
    int tid = threadIdx.x;
    int r = tid & 15, ch = tid >> 4;
    const float* xr = x + (size_t)t * NH;
    const float* gAr = gA + (size_t)e * NH * NR;
    const float* uAr = uA + (size_t)e * NH * NR;
    float sg = 0.f, su = 0.f;
    for (int j = ch * 128; j < ch * 128 + 128; ++j) {
        float xv = xr[j];
        sg += xv * gAr[j * NR + r];
        su += xv * uAr[j * NR + r];
    }
    __shared__ float red[2][16][16];
    red[0][ch][r] = sg; red[1][ch][r] = su;
    __syncthreads();
    for (int st = 8; st >= 1; st >>= 1) {
        if (ch < st) {
            red[0][ch][r] += red[0][ch + st][r];
            red[1][ch][r] += red[1][ch + st][r];
        }
        __syncthreads();
    }
    if (tid < 16) {
        xAg[p * NR + tid] = (unsigned short)f2bf(red[0][0][tid]);
        xAu[p * NR + tid] = (unsigned short)f2bf(red[1][0][tid]);
    }
}

// -------- kernel 4: gate OR up grouped GEMM --------
// 1 wave/block, tile 32 rows x 32 cols. Codes: global->VGPR coalesced b32
// (no LDS staging, no LDS code reads). A: global->VGPR dwordx4 from the
// transposed compact xcT (fully coalesced). Two statically-named buffers,
// manually unrolled x2 loop; compiler inserts exact counted vmcnt waits.
// Only remaining LDS traffic: 16 LUT gathers/step + sclb broadcast reads.
// LDS = 1K lut + 4K sclb = 5376 B.
__global__ __launch_bounds__(64, 3) void k_gu(
    const unsigned short* __restrict__ xcT,
    const int* __restrict__ gpk, const float* __restrict__ gsc,
    const int* __restrict__ upk, const float* __restrict__ usc,
    const float* __restrict__ gB, const float* __restrict__ uB,
    const unsigned short* __restrict__ xAg, const unsigned short* __restrict__ xAu,
    const int* __restrict__ expert_off,
    unsigned short* __restrict__ gu)
{
    __shared__ u32 lut[256];                  // bf16-pair dequant LUT, 1 KB
    __shared__ float sclb[32][32];            // [step][col], 4 KB

    int lane = threadIdx.x;
    int q = lane >> 5, cw = lane & 31;
    for (int i = lane; i < 256; i += 64)
        lut[i] = bfpack2(NF4_TAB[i & 15], NF4_TAB[(i >> 4) & 15]);

    int e = blockIdx.x;
    int c0 = blockIdx.y * 32;
    int mat = blockIdx.z & 1;
    int rt = blockIdx.z >> 1;                 // row-tile 0..3
    const u32* pk = (const u32*)(mat ? upk : gpk);
    const float* scp = mat ? usc : gsc;
    const float* Bp = mat ? uB : gB;
    const unsigned short* xA = mat ? xAu : xAg;

    int off = expert_off[e];
    int cnt = expert_off[e + 1] - off;
    int colg = c0 + cw;
    const size_t pkb = (size_t)e * (NH / 2) * NI;

    // stage all 32 per-step scales once per block: sclb[s][col]
    {
        const float* sg = scp + (size_t)e * (NH / NGROUP) * NI + c0;
        #pragma unroll
        for (int g = 0; g < 4; ++g)
            stage16(sg + (size_t)(g * 8 + (lane >> 3)) * NI + ((lane & 7) << 2),
                    &sclb[g * 8][0]);
    }
    asm volatile("s_waitcnt vmcnt(0)" ::: "memory");   // sclb landed

    // per-lane code base: row offset q*4, col colg
    const u32* pkc = pk + pkb + (size_t)(q << 2) * NI + colg;

    const int NS = NH / 64;                   // 32 K-steps (even)
    for (int s0 = rt * 32; s0 < cnt; s0 += 128) {
        int rr = s0 + cw; if (rr > cnt - 1) rr = cnt - 1;
        int prow = off + rr;
        // A base: chunk index = s*8 + ks*2 + q, addr = (chunk*NPAIR + prow)*8
        const unsigned short* xr = xcT + ((size_t)q * NPAIR + prow) * 8;

        auto loadC = [&](uint4* cb, int s) {  // 16 coalesced b32 code loads
            const u32* bb = pkc + (size_t)(s << 5) * NI;
            #pragma unroll
            for (int ks = 0; ks < 4; ++ks) {
                uint4 c;
                c.x = bb[(size_t)((ks << 3) + 0) * NI];
                c.y = bb[(size_t)((ks << 3) + 1) * NI];
                c.z = bb[(size_t)((ks << 3) + 2) * NI];
                c.w = bb[(size_t)((ks << 3) + 3) * NI];
                cb[ks] = c;
            }
        };
        auto loadA = [&](bf16x8* d, int s) {  // 4 coalesced dwordx4 A loads
            #pragma unroll
            for (int ks = 0; ks < 4; ++ks)
                d[ks] = *(const bf16x8*)(xr +
                            (size_t)((s << 3) + (ks << 1)) * NPAIR * 8);
        };

        uint4 Ca[4], Cb[4];                   // static-indexed (unrolled ks)
        bf16x8 Aa[4], Ab[4];
        f32x16 acc;
        #pragma unroll
        for (int i = 0; i < 16; ++i) acc[i] = 0.f;

        auto compute = [&](const uint4* cb, const bf16x8* Ar, float scl) {
            f32x16 t;
            #pragma unroll
            for (int i = 0; i < 16; ++i) t[i] = 0.f;
            #pragma unroll
            for (int ks = 0; ks < 4; ++ks) {
                uint4 w4;
                w4.x = lut[cb[ks].x & 255];
                w4.y = lut[cb[ks].y & 255];
                w4.z = lut[cb[ks].z & 255];
                w4.w = lut[cb[ks].w & 255];
                t = MFMA32(Ar[ks], asbf(w4), t, 0, 0, 0);
            }
            #pragma unroll
            for (int i = 0; i < 16; ++i) acc[i] += scl * t[i];
        };

        loadC(Ca, 0); loadA(Aa, 0);
        loadC(Cb, 1); loadA(Ab, 1);
        for (int s = 0; s < NS; s += 2) {
            compute(Ca, Aa, sclb[s][cw]);
            if (s + 2 < NS) { loadC(Ca, s + 2); loadA(Aa, s + 2); }
            compute(Cb, Ab, sclb[s + 1][cw]);
            if (s + 3 < NS) { loadC(Cb, s + 3); loadA(Ab, s + 3); }
        }

        // LoRA extension: += (x.A) . B  (K = 16)
        {
            bf16x8 la = bfzero();
            if (s0 + cw < cnt)
                la = *(const bf16x8*)(xA + (size_t)(off + s0 + cw) * NR + (q << 3));
            const float* Bq = Bp + ((size_t)e * NR + (q << 3)) * NI + colg;
            uint4 w4; u32* wp = &w4.x;
            #pragma unroll
            for (int i = 0; i < 4; ++i)
                wp[i] = bfpack2(Bq[(2 * i) * NI], Bq[(2 * i + 1) * NI]);
            acc = MFMA32(la, asbf(w4), acc, 0, 0, 0);
        }
        // epilogue: store bf16 tile. C row = (reg&3) + 8*(reg>>2) + 4*q
        unsigned short* outb = gu + (size_t)mat * NPAIR * NI;
        #pragma unroll
        for (int reg = 0; reg < 16; ++reg) {
            int rloc = (reg & 3) + 8 * (reg >> 2) + (q << 2);
            if (s0 + rloc < cnt)
                outb[(size_t)(off + s0 + rloc) * NI + colg] =
                    (unsigned short)f2bf(acc[reg]);
        }
    }
}

// -------- kernel 5: h = silu(gate)*up, written transposed hT[k/8][p][8] ----
__global__ __launch_bounds__(256) void k_swiglu(const unsigned short* __restrict__ gu,
                                                unsigned short* __restrict__ hT) {
    int i = (blockIdx.x * 256 + threadIdx.x) * 8;
    int p = i >> 10;                          // NI = 1024
    int k0 = i & 1023;
    uint4 gv = *(const uint4*)(gu + i);
    uint4 uv = *(const uint4*)(gu + (size_t)NPAIR * NI + i);
    const u32* gp = &gv.x; const u32* up = &uv.x;
    uint4 hv; u32* hp = &hv.x;
    #pragma unroll
    for (int j = 0; j < 4; ++j) {
        float g0 = bf2f(gp[j] & 0xFFFFu), g1 = bf2f(gp[j] >> 16);
        float u0 = bf2f(up[j] & 0xFFFFu), u1 = bf2f(up[j] >> 16);
        float h0 = g0 * u0 / (1.f + __expf(-g0));
        float h1 = g1 * u1 / (1.f + __expf(-g1));
        hp[j] = bfpack2(h0, h1);
    }
    *(uint4*)(hT + ((size_t)(k0 >> 3) * NPAIR + p) * 8) = hv;
}

// -------- kernel 6: hA[p][r] = h . down_A (reads transposed hT) --------
__global__ __launch_bounds__(256) void k_hA(const unsigned short* __restrict__ hT,
                                            const float* __restrict__ dA,
                                            const int* __restrict__ pexp,
                                            unsigned short* __restrict__ hA) {
    int p = blockIdx.x;
    int e = pexp[p];
    int tid = threadIdx.x;
    int r = tid & 15, ch = tid >> 4;
    const float* dAr = dA + (size_t)e * NI * NR;
    float sv = 0.f;
    for (int j = ch * 64; j < ch * 64 + 64; ++j) {
        float hv = bf2f(hT[((size_t)(j >> 3) * NPAIR + p) * 8 + (j & 7)]);
        sv += hv * dAr[j * NR + r];
    }
    __shared__ float red[16][16];
    red[ch][r] = sv;
    __syncthreads();
    for (int st = 8; st >= 1; st >>= 1) {
        if (ch < st) red[ch][r] += red[ch + st][r];
        __syncthreads();
    }
    if (tid < 16) hA[p * NR + tid] = (unsigned short)f2bf(red[0][tid]);
}

// -------- kernel 7: down GEMM (same structure as k_gu) + combine ----
// LDS = 1K lut + 2K sclb = 3328 B.
__global__ __launch_bounds__(64, 3) void k_dn(
    const unsigned short* __restrict__ hT,
    const int* __restrict__ dpk, const float* __restrict__ dsc,
    const float* __restrict__ dB,
    const unsigned short* __restrict__ hA,
    const int* __restrict__ expert_off, const int* __restrict__ ptok,
    const float* __restrict__ pw,
    float* __restrict__ out)
{
    __shared__ u32 lut[256];
    __shared__ float sclb[16][32];

    int lane = threadIdx.x;
    int q = lane >> 5, cw = lane & 31;
    for (int i = lane; i < 256; i += 64)
        lut[i] = bfpack2(NF4_TAB[i & 15], NF4_TAB[(i >> 4) & 15]);

    int e = blockIdx.x;
    int c0 = blockIdx.y * 32;
    int rt = blockIdx.z;                      // 0..3
    const u32* pk = (const u32*)dpk;

    int off = expert_off[e];
    int cnt = expert_off[e + 1] - off;
    int colg = c0 + cw;
    const size_t pkb = (size_t)e * (NI / 2) * NH;

    {
        const float* sg = dsc + (size_t)e * (NI / NGROUP) * NH + c0;
        #pragma unroll
        for (int g = 0; g < 2; ++g)
            stage16(sg + (size_t)(g * 8 + (lane >> 3)) * NH + ((lane & 7) << 2),
                    &sclb[g * 8][0]);
    }
    asm volatile("s_waitcnt vmcnt(0)" ::: "memory");

    const u32* pkc = pk + pkb + (size_t)(q << 2) * NH + colg;

    const int NS = NI / 64;                   // 16 K-steps (even)
    for (int s0 = rt * 32; s0 < cnt; s0 += 128) {
        int rr = s0 + cw; if (rr > cnt - 1) rr = cnt - 1;
        int prow = off + rr;
        const unsigned short* hr = hT + ((size_t)q * NPAIR + prow) * 8;

        auto loadC = [&](uint4* cb, int s) {
            const u32* bb = pkc + (size_t)(s << 5) * NH;
            #pragma unroll
            for (int ks = 0; ks < 4; ++ks) {
                uint4 c;
                c.x = bb[(size_t)((ks << 3) + 0) * NH];
                c.y = bb[(size_t)((ks << 3) + 1) * NH];
                c.z = bb[(size_t)((ks << 3) + 2) * NH];
                c.w = bb[(size_t)((ks << 3) + 3) * NH];
                cb[ks] = c;
            }
        };
        auto loadA = [&](bf16x8* d, int s) {
            #pragma unroll
            for (int ks = 0; ks < 4; ++ks)
                d[ks] = *(const bf16x8*)(hr +
                            (size_t)((s << 3) + (ks << 1)) * NPAIR * 8);
        };

        uint4 Ca[4], Cb[4];
        bf16x8 Aa[4], Ab[4];
        f32x16 acc;
        #pragma unroll
        for (int i = 0; i < 16; ++i) acc[i] = 0.f;

        auto compute = [&](const uint4* cb, const bf16x8* Ar, float scl) {
            f32x16 t;
            #pragma unroll
            for (int i = 0; i < 16; ++i) t[i] = 0.f;
            #pragma unroll
            for (int ks = 0; ks < 4; ++ks) {
                uint4 w4;
                w4.x = lut[cb[ks].x & 255];
                w4.y = lut[cb[ks].y & 255];
                w4.z = lut[cb[ks].z & 255];
                w4.w = lut[cb[ks].w & 255];
                t = MFMA32(Ar[ks], asbf(w4), t, 0, 0, 0);
            }
            #pragma unroll
            for (int i = 0; i < 16; ++i) acc[i] += scl * t[i];
        };

        loadC(Ca, 0); loadA(Aa, 0);
        loadC(Cb, 1); loadA(Ab, 1);
        for (int s = 0; s < NS; s += 2) {
            compute(Ca, Aa, sclb[s][cw]);
            if (s + 2 < NS) { loadC(Ca, s + 2); loadA(Aa, s + 2); }
            compute(Cb, Ab, sclb[s + 1][cw]);
            if (s + 3 < NS) { loadC(Cb, s + 3); loadA(Ab, s + 3); }
        }

        // LoRA extension: += (h.down_A) . down_B (K = 16)
        {
            bf16x8 la = bfzero();
            if (s0 + cw < cnt)
                la = *(const bf16x8*)(hA + (size_t)(off + s0 + cw) * NR + (q << 3));
            const float* Bq = dB + ((size_t)e * NR + (q << 3)) * NH + colg;
            uint4 w4; u32* wp = &w4.x;
            #pragma unroll
            for (int i = 0; i < 4; ++i)
                wp[i] = bfpack2(Bq[(2 * i) * NH], Bq[(2 * i + 1) * NH]);
            acc = MFMA32(la, asbf(w4), acc, 0, 0, 0);
        }
        // epilogue: weighted atomic combine
        #pragma unroll
        for (int reg = 0; reg < 16; ++reg) {
            int rloc = (reg & 3) + 8 * (reg >> 2) + (q << 2);
            if (s0 + rloc < cnt) {
                int p = off + s0 + rloc;
                atomicAdd(&out[(size_t)ptok[p] * NH + colg], acc[reg] * pw[p]);
            }
        }
    }
}

extern "C" void kernel_launch(void* const* d_in, const int* in_sizes, int n_in,
                              void* d_out, int out_size, void* d_ws,
                              size_t ws_size, hipStream_t stream) {
    const float* x = (const float*)d_in[0];
    const int* topk_idx = (const int*)d_in[1];
    const float* topk_w = (const float*)d_in[2];
    const int* gate_packed = (const int*)d_in[3];
    const float* gate_scales = (const float*)d_in[4];
    const int* up_packed = (const int*)d_in[5];
    const float* up_scales = (const float*)d_in[6];
    const int* down_packed = (const int*)d_in[7];
    const float* down_scales = (const float*)d_in[8];
    const float* gate_A = (const float*)d_in[9];
    const float* gate_B = (const float*)d_in[10];
    const float* up_A = (const float*)d_in[11];
    const float* up_B = (const float*)d_in[12];
    const float* down_A = (const float*)d_in[13];
    const float* down_B = (const float*)d_in[14];
    float* out = (float*)d_out;

    char* ws = (char*)d_ws;
    int* expert_off = (int*)(ws + OFF_EXPOFF);
    int* ptok = (int*)(ws + OFF_TOK);
    int* pexp = (int*)(ws + OFF_EXP);
    float* pw = (float*)(ws + OFF_W);
    unsigned short* xAg = (unsigned short*)(ws + OFF_XAG);
    unsigned short* xAu = (unsigned short*)(ws + OFF_XAU);
    unsigned short* hA = (unsigned short*)(ws + OFF_HA);
    unsigned short* xcT = (unsigned short*)(ws + OFF_XCT);
    unsigned short* gu = (unsigned short*)(ws + OFF_GU);
    unsigned short* hT = (unsigned short*)(ws + OFF_HT);

    hipMemsetAsync(d_out, 0, (size_t)NT * NH * sizeof(float), stream);

    k_route<<<1, 1024, 0, stream>>>(topk_idx, topk_w, expert_off, ptok, pexp, pw);
    k_xg<<<NPAIR, 256, 0, stream>>>(x, ptok, xcT);
    k_xA<<<NPAIR, 256, 0, stream>>>(x, gate_A, up_A, ptok, pexp, xAg, xAu);
    k_gu<<<dim3(NE, NI / 32, 8), 64, 0, stream>>>(
        xcT, gate_packed, gate_scales, up_packed, up_scales, gate_B, up_B,
        xAg, xAu, expert_off, gu);
    k_swiglu<<<(NPAIR * NI) / (256 * 8), 256, 0, stream>>>(gu, hT);
    k_hA<<<NPAIR, 256, 0, stream>>>(hT, down_A, pexp, hA);
    k_dn<<<dim3(NE, NH / 32, 4), 64, 0, stream>>>(
        hT, down_packed, down_scales, down_B, hA, expert_off, ptok, pw, out);
}

// Round 4
// 263.244 us; speedup vs baseline: 1.8644x; 1.8644x over previous
//
#include <hip/hip_runtime.h>
#include <math.h>

#define NE 8
#define NH 2048
#define NI 1024
#define NT 512
#define NTOPK 2
#define NR 16
#define NGROUP 64
#define NPAIR (NT*NTOPK)   // 1024

// compact code buffers: [e][col][kp] bytes, padded col stride (multiple of 16,
// NOT a power of two -> avoids L2 channel camping on the lane stride)
#define SPG 1040             // gate/up: K2 = NH/2 = 1024 -> stride 1040
#define SPD 528              // down:    K2 = NI/2 = 512  -> stride 528

typedef short bf16x8 __attribute__((ext_vector_type(8)));
typedef float f32x16 __attribute__((ext_vector_type(16)));
typedef unsigned int u32;

#define MFMA32 __builtin_amdgcn_mfma_f32_32x32x16_bf16

__device__ const float NF4_TAB[16] = {
    -1.0f, -0.6961928009986877f, -0.5250730514526367f, -0.39491748809814453f,
    -0.28444138169288635f, -0.18477343022823334f, -0.09105003625154495f, 0.0f,
    0.07958029955625534f, 0.16093020141124725f, 0.24611230194568634f,
    0.33791524171829224f, 0.44070982933044434f, 0.5626170039176941f,
    0.7229568362236328f, 1.0f};

// ---------------- workspace layout (bytes) ----------------
#define OFF_EXPOFF 0         // int[16]
#define OFF_TOK    256       // int[1024]
#define OFF_EXP    4352      // int[1024]
#define OFF_W      8448      // float[1024]
#define OFF_XAG    12544     // ushort[1024*16] bf16
#define OFF_XAU    45312     // ushort[1024*16]
#define OFF_HA     78080     // ushort[1024*16]
#define OFF_XCT    131072    // ushort[NH/8][NPAIR][8] transposed compact x (4 MB)
#define OFF_GU     4325376   // ushort[2*1024*1024] gate|up results (4 MB)
#define OFF_HBUF   8519680   // ushort[NPAIR*NI] row-major h (2 MB)
#define OFF_HT     10616832  // ushort[NI/8][NPAIR][8] transposed h (2 MB)
#define OFF_CG     12713984  // uchar[NE][NI][SPG] compact gate codes (8.5 MB)
#define OFF_CU     21233664  // uchar[NE][NI][SPG] compact up codes
#define OFF_CD     29753344  // uchar[NE][NH][SPD] compact down codes (8.65 MB)
                             // end = 38404096

__device__ inline u32 f2bf(float f) {
    return (__float_as_uint(f) + 0x8000u) >> 16;
}
__device__ inline u32 bfpack2(float a, float b) {
    return ((__float_as_uint(a) + 0x8000u) >> 16) |
           ((__float_as_uint(b) + 0x8000u) & 0xFFFF0000u);
}
__device__ inline bf16x8 asbf(uint4 w) {
    union { uint4 u; bf16x8 b; } c; c.u = w; return c.b;
}
__device__ inline bf16x8 bfzero() { return asbf(make_uint4(0,0,0,0)); }
__device__ inline float bf2f(u32 v) { return __uint_as_float(v << 16); }

// async global->LDS: per-lane global addr, LDS dest = wave-uniform base + lane*16
__device__ __forceinline__ void stage16(const void* g, void* l) {
    __builtin_amdgcn_global_load_lds(
        (const __attribute__((address_space(1))) u32*)g,
        (__attribute__((address_space(3))) u32*)l, 16, 0, 0);
}
#define WAITV0()  asm volatile("s_waitcnt vmcnt(0)" ::: "memory")

// -------- kernel 0: compact int32 codes -> transposed uint8 --------
// in: [e][kp (K2)][col (N)] int32 (one useful byte each)
// out: [e][col][kp] uint8, col stride SP. 32x32 tiles via LDS.
__global__ __launch_bounds__(256) void k_cmp(const u32* __restrict__ in,
                                             unsigned char* __restrict__ out,
                                             int K2, int N, int SP) {
    __shared__ unsigned char tile[32][33];
    int e = blockIdx.z;
    int kp0 = blockIdx.y * 32, c0 = blockIdx.x * 32;
    const u32* ip = in + (size_t)e * K2 * N + (size_t)kp0 * N + c0;
    int tid = threadIdx.x;
    int r = tid >> 5, c = tid & 31;
    #pragma unroll
    for (int i = 0; i < 4; ++i)
        tile[r + 8 * i][c] = (unsigned char)ip[(size_t)(r + 8 * i) * N + c];
    __syncthreads();
    int col = tid >> 3, seg = tid & 7;
    u32 w = (u32)tile[seg * 4 + 0][col] | ((u32)tile[seg * 4 + 1][col] << 8) |
            ((u32)tile[seg * 4 + 2][col] << 16) |
            ((u32)tile[seg * 4 + 3][col] << 24);
    *(u32*)(out + (size_t)e * N * SP + (size_t)(c0 + col) * SP + kp0 + seg * 4) = w;
}

// -------- kernel 1: routing compaction --------
__global__ __launch_bounds__(1024) void k_route(const int* __restrict__ idx,
                                                const float* __restrict__ w,
                                                int* expert_off, int* ptok,
                                                int* pexp, float* pw) {
    __shared__ int cnt[NE], off[NE + 1], cur[NE];
    int tid = threadIdx.x;
    if (tid < NE) cnt[tid] = 0;
    __syncthreads();
    int e = idx[tid];
    float wt = w[tid];
    int t = tid >> 1;
    atomicAdd(&cnt[e], 1);
    __syncthreads();
    if (tid == 0) {
        off[0] = 0;
        for (int i = 0; i < NE; i++) off[i + 1] = off[i] + cnt[i];
    }
    __syncthreads();
    if (tid < NE) cur[tid] = off[tid];
    __syncthreads();
    int pos = atomicAdd(&cur[e], 1);
    ptok[pos] = t; pexp[pos] = e; pw[pos] = wt;
    if (tid <= NE) expert_off[tid] = off[tid];
}

// -------- kernel 2: gather + transpose x -> xcT[k/8][p][8] bf16 --------
__global__ __launch_bounds__(256) void k_xg(const float* __restrict__ x,
                                            const int* __restrict__ ptok,
                                            unsigned short* __restrict__ xcT) {
    int p = blockIdx.x;
    int t = ptok[p];
    int k = threadIdx.x * 8;
    const float* xr = x + (size_t)t * NH + k;
    float4 v0 = *(const float4*)xr;
    float4 v1 = *(const float4*)(xr + 4);
    uint4 w;
    w.x = bfpack2(v0.x, v0.y); w.y = bfpack2(v0.z, v0.w);
    w.z = bfpack2(v1.x, v1.y); w.w = bfpack2(v1.z, v1.w);
    *(uint4*)(xcT + ((size_t)(k >> 3) * NPAIR + p) * 8) = w;
}

// -------- kernel 3: xA_g[p][r], xA_u[p][r] --------
__global__ __launch_bounds__(256) void k_xA(const float* __restrict__ x,
                                            const float* __restrict__ gA,
                                            const float* __restrict__ uA,
                                            const int* __restrict__ ptok,
                                            const int* __restrict__ pexp,
                                            unsigned short* __restrict__ xAg,
                                            unsigned short* __restrict__ xAu) {
    int p = blockIdx.x;
    int t = ptok[p], e = pexp[p];
    int tid = threadIdx.x;
    int r = tid & 15, ch = tid >> 4;
    const float* xr = x + (size_t)t * NH;
    const float* gAr = gA + (size_t)e * NH * NR;
    const float* uAr = uA + (size_t)e * NH * NR;
    float sg = 0.f, su = 0.f;
    for (int j = ch * 128; j < ch * 128 + 128; ++j) {
        float xv = xr[j];
        sg += xv * gAr[j * NR + r];
        su += xv * uAr[j * NR + r];
    }
    __shared__ float red[2][16][16];
    red[0][ch][r] = sg; red[1][ch][r] = su;
    __syncthreads();
    for (int st = 8; st >= 1; st >>= 1) {
        if (ch < st) {
            red[0][ch][r] += red[0][ch + st][r];
            red[1][ch][r] += red[1][ch + st][r];
        }
        __syncthreads();
    }
    if (tid < 16) {
        xAg[p * NR + tid] = (unsigned short)f2bf(red[0][0][tid]);
        xAu[p * NR + tid] = (unsigned short)f2bf(red[1][0][tid]);
    }
}

// -------- kernel 4: gate OR up grouped GEMM --------
// 1 wave/block, tile 32 rows x 32 cols. Codes: ONE dwordx4/step per lane from
// the compact transposed buffer (16 contiguous bytes = the lane's whole
// K-step). A: coalesced dwordx4 from xcT. Per-step k-permutation (MFMA ks
// covers source k = s*64 + q*32 + ks*8 + j, applied to BOTH A and B frags,
// dot-product invariant) makes both sides contiguous. No LDS code staging;
// only LUT gathers remain on LDS. Two statically-named buffers, unrolled x2;
// compiler inserts exact counted vmcnt (pure VGPR deps).
// LDS = 1K lut + 4K sclb = 5376 B.
__global__ __launch_bounds__(64, 3) void k_gu(
    const unsigned short* __restrict__ xcT,
    const unsigned char* __restrict__ cgp, const float* __restrict__ gsc,
    const unsigned char* __restrict__ cup, const float* __restrict__ usc,
    const float* __restrict__ gB, const float* __restrict__ uB,
    const unsigned short* __restrict__ xAg, const unsigned short* __restrict__ xAu,
    const int* __restrict__ expert_off,
    unsigned short* __restrict__ gu)
{
    __shared__ u32 lut[256];                  // bf16-pair dequant LUT, 1 KB
    __shared__ float sclb[32][32];            // [step][col], 4 KB

    int lane = threadIdx.x;
    int q = lane >> 5, cw = lane & 31;
    for (int i = lane; i < 256; i += 64)
        lut[i] = bfpack2(NF4_TAB[i & 15], NF4_TAB[(i >> 4) & 15]);

    int e = blockIdx.x;
    int c0 = blockIdx.y * 32;
    int mat = blockIdx.z & 1;
    int rt = blockIdx.z >> 1;                 // row-tile 0..3
    const unsigned char* cp = mat ? cup : cgp;
    const float* scp = mat ? usc : gsc;
    const float* Bp = mat ? uB : gB;
    const unsigned short* xA = mat ? xAu : xAg;

    int off = expert_off[e];
    int cnt = expert_off[e + 1] - off;
    int colg = c0 + cw;

    // stage all 32 per-step scales once per block: sclb[s][col]
    {
        const float* sg = scp + (size_t)e * (NH / NGROUP) * NI + c0;
        #pragma unroll
        for (int g = 0; g < 4; ++g)
            stage16(sg + (size_t)(g * 8 + (lane >> 3)) * NI + ((lane & 7) << 2),
                    &sclb[g * 8][0]);
    }
    WAITV0();                                 // sclb landed

    // per-lane code base: this lane's column, q half (16 B per step)
    const unsigned char* cb = cp + ((size_t)e * NI + colg) * SPG + (q << 4);

    const int NS = NH / 64;                   // 32 K-steps (even)
    for (int s0 = rt * 32; s0 < cnt; s0 += 128) {
        int rr = s0 + cw; if (rr > cnt - 1) rr = cnt - 1;
        int prow = off + rr;

        auto loadC = [&](uint4& c, int s) {   // 16 contiguous code bytes
            c = *(const uint4*)(cb + (s << 5));
        };
        auto loadA = [&](bf16x8* d, int s) {  // 4 coalesced dwordx4 A loads
            #pragma unroll
            for (int ks = 0; ks < 4; ++ks)
                d[ks] = *(const bf16x8*)(xcT +
                            ((size_t)((s << 3) + (q << 2) + ks) * NPAIR + prow) * 8);
        };

        uint4 C0, C1;                         // static-named (unrolled ks)
        bf16x8 Aa[4], Ab[4];
        f32x16 acc;
        #pragma unroll
        for (int i = 0; i < 16; ++i) acc[i] = 0.f;

        auto compute = [&](const uint4& cv, const bf16x8* Ar, float scl) {
            const u32* cd = &cv.x;
            f32x16 t;
            #pragma unroll
            for (int i = 0; i < 16; ++i) t[i] = 0.f;
            #pragma unroll
            for (int ks = 0; ks < 4; ++ks) {
                u32 d = cd[ks];
                uint4 w4;
                w4.x = lut[d & 255];
                w4.y = lut[(d >> 8) & 255];
                w4.z = lut[(d >> 16) & 255];
                w4.w = lut[d >> 24];
                t = MFMA32(Ar[ks], asbf(w4), t, 0, 0, 0);
            }
            #pragma unroll
            for (int i = 0; i < 16; ++i) acc[i] += scl * t[i];
        };

        loadC(C0, 0); loadA(Aa, 0);
        loadC(C1, 1); loadA(Ab, 1);
        for (int s = 0; s < NS; s += 2) {
            compute(C0, Aa, sclb[s][cw]);
            if (s + 2 < NS) { loadC(C0, s + 2); loadA(Aa, s + 2); }
            compute(C1, Ab, sclb[s + 1][cw]);
            if (s + 3 < NS) { loadC(C1, s + 3); loadA(Ab, s + 3); }
        }

        // LoRA extension: += (x.A) . B  (K = 16)
        {
            bf16x8 la = bfzero();
            if (s0 + cw < cnt)
                la = *(const bf16x8*)(xA + (size_t)(off + s0 + cw) * NR + (q << 3));
            const float* Bq = Bp + ((size_t)e * NR + (q << 3)) * NI + colg;
            uint4 w4; u32* wp = &w4.x;
            #pragma unroll
            for (int i = 0; i < 4; ++i)
                wp[i] = bfpack2(Bq[(2 * i) * NI], Bq[(2 * i + 1) * NI]);
            acc = MFMA32(la, asbf(w4), acc, 0, 0, 0);
        }
        // epilogue: store bf16 tile. C row = (reg&3) + 8*(reg>>2) + 4*q
        unsigned short* outb = gu + (size_t)mat * NPAIR * NI;
        #pragma unroll
        for (int reg = 0; reg < 16; ++reg) {
            int rloc = (reg & 3) + 8 * (reg >> 2) + (q << 2);
            if (s0 + rloc < cnt)
                outb[(size_t)(off + s0 + rloc) * NI + colg] =
                    (unsigned short)f2bf(acc[reg]);
        }
    }
}

// -------- kernel 5: h = silu(gate)*up -> hbuf (row-major) + hT (transposed) --
__global__ __launch_bounds__(256) void k_swiglu(const unsigned short* __restrict__ gu,
                                                unsigned short* __restrict__ hbuf,
                                                unsigned short* __restrict__ hT) {
    int i = (blockIdx.x * 256 + threadIdx.x) * 8;
    int p = i >> 10;                          // NI = 1024
    int k0 = i & 1023;
    uint4 gv = *(const uint4*)(gu + i);
    uint4 uv = *(const uint4*)(gu + (size_t)NPAIR * NI + i);
    const u32* gp = &gv.x; const u32* up = &uv.x;
    uint4 hv; u32* hp = &hv.x;
    #pragma unroll
    for (int j = 0; j < 4; ++j) {
        float g0 = bf2f(gp[j] & 0xFFFFu), g1 = bf2f(gp[j] >> 16);
        float u0 = bf2f(up[j] & 0xFFFFu), u1 = bf2f(up[j] >> 16);
        float h0 = g0 * u0 / (1.f + __expf(-g0));
        float h1 = g1 * u1 / (1.f + __expf(-g1));
        hp[j] = bfpack2(h0, h1);
    }
    *(uint4*)(hbuf + i) = hv;
    *(uint4*)(hT + ((size_t)(k0 >> 3) * NPAIR + p) * 8) = hv;
}

// -------- kernel 6: hA[p][r] = h . down_A (row-major hbuf) --------
__global__ __launch_bounds__(256) void k_hA(const unsigned short* __restrict__ hbuf,
                                            const float* __restrict__ dA,
                                            const int* __restrict__ pexp,
                                            unsigned short* __restrict__ hA) {
    int p = blockIdx.x;
    int e = pexp[p];
    int tid = threadIdx.x;
    int r = tid & 15, ch = tid >> 4;
    const unsigned short* hr = hbuf + (size_t)p * NI;
    const float* dAr = dA + (size_t)e * NI * NR;
    float sv = 0.f;
    for (int j = ch * 64; j < ch * 64 + 64; ++j) {
        float hv = bf2f(hr[j]);
        sv += hv * dAr[j * NR + r];
    }
    __shared__ float red[16][16];
    red[ch][r] = sv;
    __syncthreads();
    for (int st = 8; st >= 1; st >>= 1) {
        if (ch < st) red[ch][r] += red[ch + st][r];
        __syncthreads();
    }
    if (tid < 16) hA[p * NR + tid] = (unsigned short)f2bf(red[0][tid]);
}

// -------- kernel 7: down GEMM (same structure as k_gu) + combine ----
// LDS = 1K lut + 2K sclb = 3328 B.
__global__ __launch_bounds__(64, 3) void k_dn(
    const unsigned short* __restrict__ hT,
    const unsigned char* __restrict__ cdp, const float* __restrict__ dsc,
    const float* __restrict__ dB,
    const unsigned short* __restrict__ hA,
    const int* __restrict__ expert_off, const int* __restrict__ ptok,
    const float* __restrict__ pw,
    float* __restrict__ out)
{
    __shared__ u32 lut[256];
    __shared__ float sclb[16][32];

    int lane = threadIdx.x;
    int q = lane >> 5, cw = lane & 31;
    for (int i = lane; i < 256; i += 64)
        lut[i] = bfpack2(NF4_TAB[i & 15], NF4_TAB[(i >> 4) & 15]);

    int e = blockIdx.x;
    int c0 = blockIdx.y * 32;
    int rt = blockIdx.z;                      // 0..3

    int off = expert_off[e];
    int cnt = expert_off[e + 1] - off;
    int colg = c0 + cw;

    {
        const float* sg = dsc + (size_t)e * (NI / NGROUP) * NH + c0;
        #pragma unroll
        for (int g = 0; g < 2; ++g)
            stage16(sg + (size_t)(g * 8 + (lane >> 3)) * NH + ((lane & 7) << 2),
                    &sclb[g * 8][0]);
    }
    WAITV0();

    const unsigned char* cb = cdp + ((size_t)e * NH + colg) * SPD + (q << 4);

    const int NS = NI / 64;                   // 16 K-steps (even)
    for (int s0 = rt * 32; s0 < cnt; s0 += 128) {
        int rr = s0 + cw; if (rr > cnt - 1) rr = cnt - 1;
        int prow = off + rr;

        auto loadC = [&](uint4& c, int s) {
            c = *(const uint4*)(cb + (s << 5));
        };
        auto loadA = [&](bf16x8* d, int s) {
            #pragma unroll
            for (int ks = 0; ks < 4; ++ks)
                d[ks] = *(const bf16x8*)(hT +
                            ((size_t)((s << 3) + (q << 2) + ks) * NPAIR + prow) * 8);
        };

        uint4 C0, C1;
        bf16x8 Aa[4], Ab[4];
        f32x16 acc;
        #pragma unroll
        for (int i = 0; i < 16; ++i) acc[i] = 0.f;

        auto compute = [&](const uint4& cv, const bf16x8* Ar, float scl) {
            const u32* cd = &cv.x;
            f32x16 t;
            #pragma unroll
            for (int i = 0; i < 16; ++i) t[i] = 0.f;
            #pragma unroll
            for (int ks = 0; ks < 4; ++ks) {
                u32 d = cd[ks];
                uint4 w4;
                w4.x = lut[d & 255];
                w4.y = lut[(d >> 8) & 255];
                w4.z = lut[(d >> 16) & 255];
                w4.w = lut[d >> 24];
                t = MFMA32(Ar[ks], asbf(w4), t, 0, 0, 0);
            }
            #pragma unroll
            for (int i = 0; i < 16; ++i) acc[i] += scl * t[i];
        };

        loadC(C0, 0); loadA(Aa, 0);
        loadC(C1, 1); loadA(Ab, 1);
        for (int s = 0; s < NS; s += 2) {
            compute(C0, Aa, sclb[s][cw]);
            if (s + 2 < NS) { loadC(C0, s + 2); loadA(Aa, s + 2); }
            compute(C1, Ab, sclb[s + 1][cw]);
            if (s + 3 < NS) { loadC(C1, s + 3); loadA(Ab, s + 3); }
        }

        // LoRA extension: += (h.down_A) . down_B (K = 16)
        {
            bf16x8 la = bfzero();
            if (s0 + cw < cnt)
                la = *(const bf16x8*)(hA + (size_t)(off + s0 + cw) * NR + (q << 3));
            const float* Bq = dB + ((size_t)e * NR + (q << 3)) * NH + colg;
            uint4 w4; u32* wp = &w4.x;
            #pragma unroll
            for (int i = 0; i < 4; ++i)
                wp[i] = bfpack2(Bq[(2 * i) * NH], Bq[(2 * i + 1) * NH]);
            acc = MFMA32(la, asbf(w4), acc, 0, 0, 0);
        }
        // epilogue: weighted atomic combine
        #pragma unroll
        for (int reg = 0; reg < 16; ++reg) {
            int rloc = (reg & 3) + 8 * (reg >> 2) + (q << 2);
            if (s0 + rloc < cnt) {
                int p = off + s0 + rloc;
                atomicAdd(&out[(size_t)ptok[p] * NH + colg], acc[reg] * pw[p]);
            }
        }
    }
}

extern "C" void kernel_launch(void* const* d_in, const int* in_sizes, int n_in,
                              void* d_out, int out_size, void* d_ws,
                              size_t ws_size, hipStream_t stream) {
    const float* x = (const float*)d_in[0];
    const int* topk_idx = (const int*)d_in[1];
    const float* topk_w = (const float*)d_in[2];
    const int* gate_packed = (const int*)d_in[3];
    const float* gate_scales = (const float*)d_in[4];
    const int* up_packed = (const int*)d_in[5];
    const float* up_scales = (const float*)d_in[6];
    const int* down_packed = (const int*)d_in[7];
    const float* down_scales = (const float*)d_in[8];
    const float* gate_A = (const float*)d_in[9];
    const float* gate_B = (const float*)d_in[10];
    const float* up_A = (const float*)d_in[11];
    const float* up_B = (const float*)d_in[12];
    const float* down_A = (const float*)d_in[13];
    const float* down_B = (const float*)d_in[14];
    float* out = (float*)d_out;

    char* ws = (char*)d_ws;
    int* expert_off = (int*)(ws + OFF_EXPOFF);
    int* ptok = (int*)(ws + OFF_TOK);
    int* pexp = (int*)(ws + OFF_EXP);
    float* pw = (float*)(ws + OFF_W);
    unsigned short* xAg = (unsigned short*)(ws + OFF_XAG);
    unsigned short* xAu = (unsigned short*)(ws + OFF_XAU);
    unsigned short* hA = (unsigned short*)(ws + OFF_HA);
    unsigned short* xcT = (unsigned short*)(ws + OFF_XCT);
    unsigned short* gu = (unsigned short*)(ws + OFF_GU);
    unsigned short* hbuf = (unsigned short*)(ws + OFF_HBUF);
    unsigned short* hT = (unsigned short*)(ws + OFF_HT);
    unsigned char* cg = (unsigned char*)(ws + OFF_CG);
    unsigned char* cu = (unsigned char*)(ws + OFF_CU);
    unsigned char* cd = (unsigned char*)(ws + OFF_CD);

    hipMemsetAsync(d_out, 0, (size_t)NT * NH * sizeof(float), stream);

    // weight compact+transpose prepass
    k_cmp<<<dim3(NI / 32, (NH / 2) / 32, NE), 256, 0, stream>>>(
        (const u32*)gate_packed, cg, NH / 2, NI, SPG);
    k_cmp<<<dim3(NI / 32, (NH / 2) / 32, NE), 256, 0, stream>>>(
        (const u32*)up_packed, cu, NH / 2, NI, SPG);
    k_cmp<<<dim3(NH / 32, (NI / 2) / 32, NE), 256, 0, stream>>>(
        (const u32*)down_packed, cd, NI / 2, NH, SPD);

    k_route<<<1, 1024, 0, stream>>>(topk_idx, topk_w, expert_off, ptok, pexp, pw);
    k_xg<<<NPAIR, 256, 0, stream>>>(x, ptok, xcT);
    k_xA<<<NPAIR, 256, 0, stream>>>(x, gate_A, up_A, ptok, pexp, xAg, xAu);
    k_gu<<<dim3(NE, NI / 32, 8), 64, 0, stream>>>(
        xcT, cg, gate_scales, cu, up_scales, gate_B, up_B,
        xAg, xAu, expert_off, gu);
    k_swiglu<<<(NPAIR * NI) / (256 * 8), 256, 0, stream>>>(gu, hbuf, hT);
    k_hA<<<NPAIR, 256, 0, stream>>>(hbuf, down_A, pexp, hA);
    k_dn<<<dim3(NE, NH / 32, 4), 64, 0, stream>>>(
        hT, cd, down_scales, down_B, hA, expert_off, ptok, pw, out);
}